// Round 1
// baseline (2461.451 us; speedup 1.0000x reference)
//
#include <hip/hip_runtime.h>

typedef _Float16 half8 __attribute__((ext_vector_type(8)));
typedef _Float16 half4v __attribute__((ext_vector_type(4)));
typedef float f32x4 __attribute__((ext_vector_type(4)));

#define B_ 64
#define S_ 512
#define I_ 1024
#define H_ 1024
#define OUT_MAIN 33554432L   // B*S*H

// ws layout (bytes)
#define WS_PRE   0L          // pre_f16: 32768*1024*2 = 67108864
#define WS_WIH   67108864L   // Wih f16: 2 MB
#define WS_WHH   69206016L   // Whh f16: 2 MB
#define WS_HBUF  71303168L   // h double buffer: 2*256*1024*2 = 1 MB
#define WS_BIAS  72351744L   // bias fp32: 4 KB
#define WS_CTR   72355840L   // 8 counters, 128-B strided

// ---------------------------------------------------------------------------
// prep: convert weights + initial hidden to f16, bias sum, zero counters
// ---------------------------------------------------------------------------
__global__ __launch_bounds__(256) void prep_kernel(
    const float* __restrict__ wih, const float* __restrict__ whh,
    const float* __restrict__ hid, const float* __restrict__ bih,
    const float* __restrict__ bhh,
    _Float16* __restrict__ wihf, _Float16* __restrict__ whhf,
    _Float16* __restrict__ hbuf, float* __restrict__ bias,
    unsigned* __restrict__ ctr) {
  int tid = blockIdx.x * 256 + threadIdx.x;
  int np = gridDim.x * 256;
  for (int i = tid; i < 262144; i += np) {
    float4 v = ((const float4*)wih)[i];
    half4v h; h[0]=(_Float16)v.x; h[1]=(_Float16)v.y; h[2]=(_Float16)v.z; h[3]=(_Float16)v.w;
    ((half4v*)wihf)[i] = h;
  }
  for (int i = tid; i < 262144; i += np) {
    float4 v = ((const float4*)whh)[i];
    half4v h; h[0]=(_Float16)v.x; h[1]=(_Float16)v.y; h[2]=(_Float16)v.z; h[3]=(_Float16)v.w;
    ((half4v*)whhf)[i] = h;
  }
  // hidden_state [4,64,1024] flat == hbuf[q=r*64+b][j] flat (identity)
  for (int i = tid; i < 65536; i += np) {
    float4 v = ((const float4*)hid)[i];
    half4v h; h[0]=(_Float16)v.x; h[1]=(_Float16)v.y; h[2]=(_Float16)v.z; h[3]=(_Float16)v.w;
    ((half4v*)hbuf)[i] = h;
  }
  for (int i = tid; i < 1024; i += np) bias[i] = bih[i] + bhh[i];
  if (tid < 8) ctr[tid * 32] = 0u;
}

// ---------------------------------------------------------------------------
// gemm_pre: pre[m][n] = sum_k x[m][k] * Wih[n][k]   (f16 MFMA, fp32 acc)
// 128x128 tile, BK=64. A staged fp32->f16 via VGPR; B via global_load_lds.
// LDS layout: 16-B chunk (row,kkh) stored at slot row*8 + (kkh ^ (row&7)).
// ---------------------------------------------------------------------------
__global__ __launch_bounds__(256, 2) void gemm_pre(
    const float* __restrict__ x, const _Float16* __restrict__ wih,
    _Float16* __restrict__ pre) {
  __shared__ _Float16 Ash[128 * 64];
  __shared__ _Float16 Bsh[128 * 64];
  int tid = threadIdx.x;
  int lane = tid & 63, wid = tid >> 6;
  int l15 = lane & 15, quad = lane >> 4;
  int mt = blockIdx.x >> 3, nt = blockIdx.x & 7;
  int m0 = mt * 128, n0 = nt * 128;
  int wm = (wid >> 1) * 64, wn = (wid & 1) * 64;
  f32x4 acc[4][4] = {};

  for (int ko = 0; ko < 16; ++ko) {
    int k0 = ko * 64;
    // stage A (fp32 -> f16)
#pragma unroll
    for (int p = 0; p < 4; ++p) {
      int s = p * 256 + tid;
      int row = s >> 3;
      int kkh = (s & 7) ^ (row & 7);
      const float* g = x + (long)(m0 + row) * 1024 + k0 + kkh * 8;
      float4 v0 = ((const float4*)g)[0];
      float4 v1 = ((const float4*)g)[1];
      half8 hv;
      hv[0]=(_Float16)v0.x; hv[1]=(_Float16)v0.y; hv[2]=(_Float16)v0.z; hv[3]=(_Float16)v0.w;
      hv[4]=(_Float16)v1.x; hv[5]=(_Float16)v1.y; hv[6]=(_Float16)v1.z; hv[7]=(_Float16)v1.w;
      *(half8*)(Ash + (long)s * 8) = hv;
    }
    // stage B (already f16) via async global->LDS, 16 B/lane
#pragma unroll
    for (int p = 0; p < 4; ++p) {
      int s = p * 256 + tid;
      int row = s >> 3;
      int kkh = (s & 7) ^ (row & 7);
      const _Float16* g = wih + (long)(n0 + row) * 1024 + k0 + kkh * 8;
      __builtin_amdgcn_global_load_lds(
          (const __attribute__((address_space(1))) void*)g,
          (__attribute__((address_space(3))) void*)(Bsh + (p * 256 + wid * 64) * 8),
          16, 0, 0);
    }
    __syncthreads();
#pragma unroll
    for (int kk = 0; kk < 2; ++kk) {
      half8 af[4], bf[4];
      int kkh = kk * 4 + quad;
#pragma unroll
      for (int i = 0; i < 4; ++i) {
        int ra = wm + i * 16 + l15;
        af[i] = *(const half8*)(Ash + (ra * 8 + (kkh ^ (ra & 7))) * 8);
        int rb = wn + i * 16 + l15;
        bf[i] = *(const half8*)(Bsh + (rb * 8 + (kkh ^ (rb & 7))) * 8);
      }
#pragma unroll
      for (int i = 0; i < 4; ++i)
#pragma unroll
        for (int j = 0; j < 4; ++j)
          acc[i][j] = __builtin_amdgcn_mfma_f32_16x16x32_f16(af[i], bf[j], acc[i][j], 0, 0, 0);
    }
    __syncthreads();
  }
  // epilogue: C/D layout col=lane&15, row=quad*4+r
#pragma unroll
  for (int i = 0; i < 4; ++i)
#pragma unroll
    for (int j = 0; j < 4; ++j)
#pragma unroll
      for (int r = 0; r < 4; ++r) {
        int row = m0 + wm + i * 16 + quad * 4 + r;
        int col = n0 + wn + j * 16 + l15;
        pre[(long)row * 1024 + col] = (_Float16)acc[i][j][r];
      }
}

// ---------------------------------------------------------------------------
// rnn: 128 sequential steps. 8 rowgroups (32 chains) x 32 colgroups (32 cols).
// Whh fragments register-resident; h double-buffered; per-rowgroup sync.
// ---------------------------------------------------------------------------
__global__ __launch_bounds__(128, 1) void rnn_kernel(
    const _Float16* __restrict__ pre, const _Float16* __restrict__ whhf,
    _Float16* __restrict__ hbuf, const float* __restrict__ bias,
    unsigned* ctr, float* __restrict__ out) {
  int rg = blockIdx.x & 7;   // rowgroup -> same XCD under round-robin heuristic
  int cg = blockIdx.x >> 3;  // colgroup 0..31
  int wid = threadIdx.x >> 6;
  int lane = threadIdx.x & 63;
  int l15 = lane & 15, quad = lane >> 4;
  int n = cg * 32 + wid * 16 + l15;  // this lane's output column (fixed)
  int q0 = rg * 32;

  // preload Whh fragments for our 16 columns, all K (32 kk-steps)
  half8 bfrag[32];
  const _Float16* wp = whhf + (long)n * 1024 + quad * 8;
#pragma unroll
  for (int kk = 0; kk < 32; ++kk) bfrag[kk] = *(const half8*)(wp + kk * 32);
  float bn = bias[n];

  // per-lane output bases: rows q = q0 + t*16 + quad*4 + r
  long obase[2][4];
  int hidx[2][4];
#pragma unroll
  for (int t = 0; t < 2; ++t)
#pragma unroll
    for (int r = 0; r < 4; ++r) {
      int q = q0 + t * 16 + quad * 4 + r;
      int b = q & 63, rr = q >> 6;
      obase[t][r] = (long)(b * 512 + rr) * 1024 + n;
      hidx[t][r] = q * 1024 + n;
    }
  unsigned* myctr = ctr + rg * 32;
  int arow = q0 + l15;

  for (int k = 0; k < 128; ++k) {
    const _Float16* hcur = hbuf + (long)(k & 1) * 262144;
    _Float16* hnxt = hbuf + (long)((k + 1) & 1) * 262144;
    const _Float16* ap = hcur + (long)arow * 1024 + quad * 8;
    f32x4 acc0 = {0.f, 0.f, 0.f, 0.f}, acc1 = {0.f, 0.f, 0.f, 0.f};
#pragma unroll
    for (int kk = 0; kk < 32; ++kk) {
      half8 a0 = *(const half8*)(ap + kk * 32);
      half8 a1 = *(const half8*)(ap + 16 * 1024 + kk * 32);
      acc0 = __builtin_amdgcn_mfma_f32_16x16x32_f16(a0, bfrag[kk], acc0, 0, 0, 0);
      acc1 = __builtin_amdgcn_mfma_f32_16x16x32_f16(a1, bfrag[kk], acc1, 0, 0, 0);
    }
#pragma unroll
    for (int t = 0; t < 2; ++t) {
      f32x4 acc = t ? acc1 : acc0;
#pragma unroll
      for (int r = 0; r < 4; ++r) {
        long oi = obase[t][r] + (long)k * 4096;
        float z = acc[r] + bn + (float)pre[oi];
        float e = __expf(2.f * z);
        float h = 1.f - 2.f * __builtin_amdgcn_rcpf(e + 1.f);
        out[oi] = h;
        hnxt[hidx[t][r]] = (_Float16)h;
        if (k == 127) out[OUT_MAIN + hidx[t][r]] = h;
      }
    }
    if (k < 127) {
      __syncthreads();  // drains vmem stores to L2 before fence
      if (threadIdx.x == 0) {
        __threadfence();            // L2 writeback (cross-XCD visibility)
        atomicAdd(myctr, 1u);
        unsigned tgt = (unsigned)(32 * (k + 1));
        while (__hip_atomic_load(myctr, __ATOMIC_RELAXED, __HIP_MEMORY_SCOPE_AGENT) < tgt)
          __builtin_amdgcn_s_sleep(2);
        __threadfence();            // acquire: invalidate stale L1/L2
      }
      __syncthreads();
    }
  }
}

// ---------------------------------------------------------------------------
extern "C" void kernel_launch(void* const* d_in, const int* in_sizes, int n_in,
                              void* d_out, int out_size, void* d_ws, size_t ws_size,
                              hipStream_t stream) {
  const float* x   = (const float*)d_in[0];
  const float* hid = (const float*)d_in[1];
  const float* wih = (const float*)d_in[2];
  const float* whh = (const float*)d_in[3];
  const float* bih = (const float*)d_in[4];
  const float* bhh = (const float*)d_in[5];
  char* ws = (char*)d_ws;
  _Float16* pre  = (_Float16*)(ws + WS_PRE);
  _Float16* wihf = (_Float16*)(ws + WS_WIH);
  _Float16* whhf = (_Float16*)(ws + WS_WHH);
  _Float16* hbuf = (_Float16*)(ws + WS_HBUF);
  float* bias    = (float*)(ws + WS_BIAS);
  unsigned* ctr  = (unsigned*)(ws + WS_CTR);
  float* out     = (float*)d_out;

  hipLaunchKernelGGL(prep_kernel, dim3(256), dim3(256), 0, stream,
                     wih, whh, hid, bih, bhh, wihf, whhf, hbuf, bias, ctr);
  hipLaunchKernelGGL(gemm_pre, dim3(2048), dim3(256), 0, stream, x, wihf, pre);
  hipLaunchKernelGGL(rnn_kernel, dim3(256), dim3(128), 0, stream,
                     pre, whhf, hbuf, bias, ctr, out);
}

// Round 2
// 1150.420 us; speedup vs baseline: 2.1396x; 2.1396x over previous
//
#include <hip/hip_runtime.h>

typedef _Float16 half8 __attribute__((ext_vector_type(8)));
typedef _Float16 half4v __attribute__((ext_vector_type(4)));
typedef float f32x4 __attribute__((ext_vector_type(4)));

#define OUT_MAIN 33554432L   // B*S*H

// ws layout (bytes)
#define WS_PRE   0L          // pre_f16 (+bias folded): 32768*1024*2 = 67108864
#define WS_WIH   67108864L   // Wih f16: 2 MB
#define WS_WHH   69206016L   // Whh f16: 2 MB
#define WS_HBUF  71303168L   // h double buffer: 2*256*1024*2 = 1 MB
#define WS_BIAS  72351744L   // bias fp32: 4 KB
#define WS_CTR   72355840L   // 8 counters, 128-B strided

// Agent-scope relaxed atomics: bypass L1/L2, resolve at the Infinity Cache
// (the cross-XCD coherence point). No fences -> no buffer_wbl2/buffer_inv.
__device__ __forceinline__ half8 ic_load16(const _Float16* p) {
  unsigned long long lo = __hip_atomic_load((unsigned long long*)p,
      __ATOMIC_RELAXED, __HIP_MEMORY_SCOPE_AGENT);
  unsigned long long hi = __hip_atomic_load((unsigned long long*)p + 1,
      __ATOMIC_RELAXED, __HIP_MEMORY_SCOPE_AGENT);
  union { unsigned long long u[2]; half8 h; } cv;
  cv.u[0] = lo; cv.u[1] = hi;
  return cv.h;
}

// ---------------------------------------------------------------------------
// prep: convert weights + initial hidden to f16, bias sum, zero counters
// ---------------------------------------------------------------------------
__global__ __launch_bounds__(256) void prep_kernel(
    const float* __restrict__ wih, const float* __restrict__ whh,
    const float* __restrict__ hid, const float* __restrict__ bih,
    const float* __restrict__ bhh,
    _Float16* __restrict__ wihf, _Float16* __restrict__ whhf,
    _Float16* __restrict__ hbuf, float* __restrict__ bias,
    unsigned* __restrict__ ctr) {
  int tid = blockIdx.x * 256 + threadIdx.x;
  int np = gridDim.x * 256;
  for (int i = tid; i < 262144; i += np) {
    float4 v = ((const float4*)wih)[i];
    half4v h; h[0]=(_Float16)v.x; h[1]=(_Float16)v.y; h[2]=(_Float16)v.z; h[3]=(_Float16)v.w;
    ((half4v*)wihf)[i] = h;
  }
  for (int i = tid; i < 262144; i += np) {
    float4 v = ((const float4*)whh)[i];
    half4v h; h[0]=(_Float16)v.x; h[1]=(_Float16)v.y; h[2]=(_Float16)v.z; h[3]=(_Float16)v.w;
    ((half4v*)whhf)[i] = h;
  }
  for (int i = tid; i < 65536; i += np) {
    float4 v = ((const float4*)hid)[i];
    half4v h; h[0]=(_Float16)v.x; h[1]=(_Float16)v.y; h[2]=(_Float16)v.z; h[3]=(_Float16)v.w;
    ((half4v*)hbuf)[i] = h;
  }
  for (int i = tid; i < 1024; i += np) bias[i] = bih[i] + bhh[i];
  if (tid < 8) ctr[tid * 32] = 0u;
}

// ---------------------------------------------------------------------------
// gemm_pre: pre[m][n] = sum_k x[m][k]*Wih[n][k] + bias[n]
// ---------------------------------------------------------------------------
__global__ __launch_bounds__(256, 2) void gemm_pre(
    const float* __restrict__ x, const _Float16* __restrict__ wih,
    const float* __restrict__ bias, _Float16* __restrict__ pre) {
  __shared__ _Float16 Ash[128 * 64];
  __shared__ _Float16 Bsh[128 * 64];
  int tid = threadIdx.x;
  int lane = tid & 63, wid = tid >> 6;
  int l15 = lane & 15, quad = lane >> 4;
  int mt = blockIdx.x >> 3, nt = blockIdx.x & 7;
  int m0 = mt * 128, n0 = nt * 128;
  int wm = (wid >> 1) * 64, wn = (wid & 1) * 64;
  f32x4 acc[4][4] = {};

  for (int ko = 0; ko < 16; ++ko) {
    int k0 = ko * 64;
#pragma unroll
    for (int p = 0; p < 4; ++p) {
      int s = p * 256 + tid;
      int row = s >> 3;
      int kkh = (s & 7) ^ (row & 7);
      const float* g = x + (long)(m0 + row) * 1024 + k0 + kkh * 8;
      float4 v0 = ((const float4*)g)[0];
      float4 v1 = ((const float4*)g)[1];
      half8 hv;
      hv[0]=(_Float16)v0.x; hv[1]=(_Float16)v0.y; hv[2]=(_Float16)v0.z; hv[3]=(_Float16)v0.w;
      hv[4]=(_Float16)v1.x; hv[5]=(_Float16)v1.y; hv[6]=(_Float16)v1.z; hv[7]=(_Float16)v1.w;
      *(half8*)(Ash + (long)s * 8) = hv;
    }
#pragma unroll
    for (int p = 0; p < 4; ++p) {
      int s = p * 256 + tid;
      int row = s >> 3;
      int kkh = (s & 7) ^ (row & 7);
      const _Float16* g = wih + (long)(n0 + row) * 1024 + k0 + kkh * 8;
      __builtin_amdgcn_global_load_lds(
          (const __attribute__((address_space(1))) void*)g,
          (__attribute__((address_space(3))) void*)(Bsh + (p * 256 + wid * 64) * 8),
          16, 0, 0);
    }
    __syncthreads();
#pragma unroll
    for (int kk = 0; kk < 2; ++kk) {
      half8 af[4], bf[4];
      int kkh = kk * 4 + quad;
#pragma unroll
      for (int i = 0; i < 4; ++i) {
        int ra = wm + i * 16 + l15;
        af[i] = *(const half8*)(Ash + (ra * 8 + (kkh ^ (ra & 7))) * 8);
        int rb = wn + i * 16 + l15;
        bf[i] = *(const half8*)(Bsh + (rb * 8 + (kkh ^ (rb & 7))) * 8);
      }
#pragma unroll
      for (int i = 0; i < 4; ++i)
#pragma unroll
        for (int j = 0; j < 4; ++j)
          acc[i][j] = __builtin_amdgcn_mfma_f32_16x16x32_f16(af[i], bf[j], acc[i][j], 0, 0, 0);
    }
    __syncthreads();
  }
#pragma unroll
  for (int i = 0; i < 4; ++i)
#pragma unroll
    for (int j = 0; j < 4; ++j) {
      int col = n0 + wn + j * 16 + l15;
      float bv = bias[col];
#pragma unroll
      for (int r = 0; r < 4; ++r) {
        int row = m0 + wm + i * 16 + quad * 4 + r;
        pre[(long)row * 1024 + col] = (_Float16)(acc[i][j][r] + bv);
      }
    }
}

// ---------------------------------------------------------------------------
// rnn v2: 64 blocks x 256 thr. Block = (rowgroup rg = blk&7, colblock cg).
// Wave w = K-quarter [w*256, w*256+256) over cols [cg*128, +128).
// Whh register-resident (256 VGPR/wave). Partials reduced via LDS (f16).
// h exchange + sync via IC atomics; only 8 blocks per rowgroup sync.
// ---------------------------------------------------------------------------
__global__ __launch_bounds__(256, 1) void rnn_kernel(
    const _Float16* __restrict__ pre, const _Float16* __restrict__ whhf,
    _Float16* __restrict__ hbuf, unsigned* ctr, float* __restrict__ out) {
  __shared__ _Float16 part[4][128][36];  // [kwave][col][row+pad] f16, 36 KB
  const int rg = blockIdx.x & 7, cg = blockIdx.x >> 3;
  const int tid = threadIdx.x;
  const int w = tid >> 6, lane = tid & 63;
  const int l15 = lane & 15, quad = lane >> 4;
  const int q0 = rg * 32, c0 = cg * 128;

  // B fragments: 128 cols x 256 K (quarter w), 64 x half8 = 256 VGPR
  half8 bf[8][8];
#pragma unroll
  for (int kk = 0; kk < 8; ++kk)
#pragma unroll
    for (int j = 0; j < 8; ++j)
      bf[kk][j] = *(const half8*)(whhf + (long)(c0 + j * 16 + l15) * 1024 +
                                  w * 256 + kk * 32 + quad * 8);

  // epilogue ownership: 4 rows x 4 consecutive cols per thread
  const int oc = (tid & 31) * 4;
  const int orow = (tid >> 5) * 4;
  long obase[4];
  int hoff[4];
#pragma unroll
  for (int r = 0; r < 4; ++r) {
    int q = q0 + orow + r;
    int b = q & 63, rr = q >> 6;
    obase[r] = (long)(b * 512 + rr) * 1024 + c0 + oc;
    hoff[r] = q * 1024 + c0 + oc;
  }
  unsigned* myctr = ctr + rg * 32;
  const int arow = q0 + l15;

  for (int k = 0; k < 128; ++k) {
    const _Float16* hcur = hbuf + (long)(k & 1) * 262144;
    _Float16* hnxt = hbuf + (long)((k + 1) & 1) * 262144;
    // prefetch pre (read-only, normal cached loads; consumed in epilogue)
    half4v pv[4];
#pragma unroll
    for (int r = 0; r < 4; ++r)
      pv[r] = *(const half4v*)(pre + obase[r] + (long)k * 4096);
    // A fragments from IC (16 KB per wave per step)
    const _Float16* ap = hcur + (long)arow * 1024 + w * 256 + quad * 8;
    half8 a0[8], a1[8];
#pragma unroll
    for (int kk = 0; kk < 8; ++kk) {
      a0[kk] = ic_load16(ap + kk * 32);
      a1[kk] = ic_load16(ap + 16 * 1024 + kk * 32);
    }
    f32x4 acc[2][8] = {};
#pragma unroll
    for (int kk = 0; kk < 8; ++kk)
#pragma unroll
      for (int j = 0; j < 8; ++j) {
        acc[0][j] = __builtin_amdgcn_mfma_f32_16x16x32_f16(a0[kk], bf[kk][j], acc[0][j], 0, 0, 0);
        acc[1][j] = __builtin_amdgcn_mfma_f32_16x16x32_f16(a1[kk], bf[kk][j], acc[1][j], 0, 0, 0);
      }
    // partial sums -> LDS (f16)
#pragma unroll
    for (int t = 0; t < 2; ++t)
#pragma unroll
      for (int j = 0; j < 8; ++j) {
        half4v hv;
#pragma unroll
        for (int r = 0; r < 4; ++r) hv[r] = (_Float16)acc[t][j][r];
        *(half4v*)&part[w][j * 16 + l15][t * 16 + quad * 4] = hv;
      }
    __syncthreads();
    // reduce 4 partials + pre, tanh, store
    float z[4][4];
#pragma unroll
    for (int r = 0; r < 4; ++r)
#pragma unroll
      for (int c = 0; c < 4; ++c) z[r][c] = (float)pv[r][c];
#pragma unroll
    for (int w4 = 0; w4 < 4; ++w4)
#pragma unroll
      for (int c = 0; c < 4; ++c) {
        half4v p = *(const half4v*)&part[w4][oc + c][orow];
#pragma unroll
        for (int r = 0; r < 4; ++r) z[r][c] += (float)p[r];
      }
#pragma unroll
    for (int r = 0; r < 4; ++r) {
      f32x4 ov;
      union { _Float16 hh[4]; unsigned long long u; } pk;
#pragma unroll
      for (int c = 0; c < 4; ++c) {
        float e = __expf(2.f * z[r][c]);
        float h = 1.f - 2.f * __builtin_amdgcn_rcpf(e + 1.f);
        ov[c] = h;
        pk.hh[c] = (_Float16)h;
      }
      *(f32x4*)(out + obase[r] + (long)k * 4096) = ov;
      if (k < 127)
        __hip_atomic_store((unsigned long long*)(hnxt + hoff[r]), pk.u,
                           __ATOMIC_RELAXED, __HIP_MEMORY_SCOPE_AGENT);
      else
        *(f32x4*)(out + OUT_MAIN + hoff[r]) = ov;
    }
    if (k < 127) {
      __syncthreads();  // drains this block's h stores (vmcnt(0) before barrier)
      if (tid == 0) {
        __hip_atomic_fetch_add(myctr, 1u, __ATOMIC_RELAXED, __HIP_MEMORY_SCOPE_AGENT);
        unsigned tgt = 8u * (unsigned)(k + 1);
        while (__hip_atomic_load(myctr, __ATOMIC_RELAXED, __HIP_MEMORY_SCOPE_AGENT) < tgt)
          __builtin_amdgcn_s_sleep(1);
      }
      __syncthreads();
    }
  }
}

// ---------------------------------------------------------------------------
extern "C" void kernel_launch(void* const* d_in, const int* in_sizes, int n_in,
                              void* d_out, int out_size, void* d_ws, size_t ws_size,
                              hipStream_t stream) {
  const float* x   = (const float*)d_in[0];
  const float* hid = (const float*)d_in[1];
  const float* wih = (const float*)d_in[2];
  const float* whh = (const float*)d_in[3];
  const float* bih = (const float*)d_in[4];
  const float* bhh = (const float*)d_in[5];
  char* ws = (char*)d_ws;
  _Float16* pre  = (_Float16*)(ws + WS_PRE);
  _Float16* wihf = (_Float16*)(ws + WS_WIH);
  _Float16* whhf = (_Float16*)(ws + WS_WHH);
  _Float16* hbuf = (_Float16*)(ws + WS_HBUF);
  float* bias    = (float*)(ws + WS_BIAS);
  unsigned* ctr  = (unsigned*)(ws + WS_CTR);
  float* out     = (float*)d_out;

  hipLaunchKernelGGL(prep_kernel, dim3(256), dim3(256), 0, stream,
                     wih, whh, hid, bih, bhh, wihf, whhf, hbuf, bias, ctr);
  hipLaunchKernelGGL(gemm_pre, dim3(2048), dim3(256), 0, stream, x, wihf, bias, pre);
  hipLaunchKernelGGL(rnn_kernel, dim3(64), dim3(256), 0, stream,
                     pre, whhf, hbuf, ctr, out);
}

// Round 3
// 974.295 us; speedup vs baseline: 2.5264x; 1.1808x over previous
//
#include <hip/hip_runtime.h>

typedef _Float16 half8 __attribute__((ext_vector_type(8)));
typedef _Float16 half4v __attribute__((ext_vector_type(4)));
typedef float f32x4 __attribute__((ext_vector_type(4)));

#define OUT_MAIN 33554432L   // B*S*H

// ws layout (bytes)
#define WS_PRE   0L          // pre_f16 (+bias folded): 67108864
#define WS_WIH   67108864L   // Wih f16: 2 MB
#define WS_WHH   69206016L   // Whh f16: 2 MB
#define WS_HBUF  71303168L   // h double buffer: 2*256*1024*2 = 1 MB
#define WS_BIAS  72351744L   // bias fp32: 4 KB
#define WS_CTR   72355840L   // 128 flags x 128 B = 16 KB

// Agent-scope relaxed atomics resolve at the Infinity Cache (memory-side,
// cross-XCD coherent). No fences -> no buffer_wbl2/buffer_inv.
__device__ __forceinline__ half8 ic_load16(const _Float16* p) {
  unsigned long long lo = __hip_atomic_load((unsigned long long*)p,
      __ATOMIC_RELAXED, __HIP_MEMORY_SCOPE_AGENT);
  unsigned long long hi = __hip_atomic_load((unsigned long long*)p + 1,
      __ATOMIC_RELAXED, __HIP_MEMORY_SCOPE_AGENT);
  union { unsigned long long u[2]; half8 h; } cv;
  cv.u[0] = lo; cv.u[1] = hi;
  return cv.h;
}

// ---------------------------------------------------------------------------
__global__ __launch_bounds__(256) void prep_kernel(
    const float* __restrict__ wih, const float* __restrict__ whh,
    const float* __restrict__ hid, const float* __restrict__ bih,
    const float* __restrict__ bhh,
    _Float16* __restrict__ wihf, _Float16* __restrict__ whhf,
    _Float16* __restrict__ hbuf, float* __restrict__ bias,
    unsigned* __restrict__ ctr) {
  int tid = blockIdx.x * 256 + threadIdx.x;
  int np = gridDim.x * 256;
  for (int i = tid; i < 262144; i += np) {
    float4 v = ((const float4*)wih)[i];
    half4v h; h[0]=(_Float16)v.x; h[1]=(_Float16)v.y; h[2]=(_Float16)v.z; h[3]=(_Float16)v.w;
    ((half4v*)wihf)[i] = h;
  }
  for (int i = tid; i < 262144; i += np) {
    float4 v = ((const float4*)whh)[i];
    half4v h; h[0]=(_Float16)v.x; h[1]=(_Float16)v.y; h[2]=(_Float16)v.z; h[3]=(_Float16)v.w;
    ((half4v*)whhf)[i] = h;
  }
  for (int i = tid; i < 65536; i += np) {
    float4 v = ((const float4*)hid)[i];
    half4v h; h[0]=(_Float16)v.x; h[1]=(_Float16)v.y; h[2]=(_Float16)v.z; h[3]=(_Float16)v.w;
    ((half4v*)hbuf)[i] = h;
  }
  for (int i = tid; i < 1024; i += np) bias[i] = bih[i] + bhh[i];
  for (int i = tid; i < 4096; i += np) ctr[i] = 0u;
}

// ---------------------------------------------------------------------------
// gemm_pre: pre[m][n] = sum_k x[m][k]*Wih[n][k] + bias[n]
// ---------------------------------------------------------------------------
__global__ __launch_bounds__(256, 2) void gemm_pre(
    const float* __restrict__ x, const _Float16* __restrict__ wih,
    const float* __restrict__ bias, _Float16* __restrict__ pre) {
  __shared__ _Float16 Ash[128 * 64];
  __shared__ _Float16 Bsh[128 * 64];
  int tid = threadIdx.x;
  int lane = tid & 63, wid = tid >> 6;
  int l15 = lane & 15, quad = lane >> 4;
  int mt = blockIdx.x >> 3, nt = blockIdx.x & 7;
  int m0 = mt * 128, n0 = nt * 128;
  int wm = (wid >> 1) * 64, wn = (wid & 1) * 64;
  f32x4 acc[4][4] = {};

  for (int ko = 0; ko < 16; ++ko) {
    int k0 = ko * 64;
#pragma unroll
    for (int p = 0; p < 4; ++p) {
      int s = p * 256 + tid;
      int row = s >> 3;
      int kkh = (s & 7) ^ (row & 7);
      const float* g = x + (long)(m0 + row) * 1024 + k0 + kkh * 8;
      float4 v0 = ((const float4*)g)[0];
      float4 v1 = ((const float4*)g)[1];
      half8 hv;
      hv[0]=(_Float16)v0.x; hv[1]=(_Float16)v0.y; hv[2]=(_Float16)v0.z; hv[3]=(_Float16)v0.w;
      hv[4]=(_Float16)v1.x; hv[5]=(_Float16)v1.y; hv[6]=(_Float16)v1.z; hv[7]=(_Float16)v1.w;
      *(half8*)(Ash + (long)s * 8) = hv;
    }
#pragma unroll
    for (int p = 0; p < 4; ++p) {
      int s = p * 256 + tid;
      int row = s >> 3;
      int kkh = (s & 7) ^ (row & 7);
      const _Float16* g = wih + (long)(n0 + row) * 1024 + k0 + kkh * 8;
      __builtin_amdgcn_global_load_lds(
          (const __attribute__((address_space(1))) void*)g,
          (__attribute__((address_space(3))) void*)(Bsh + (p * 256 + wid * 64) * 8),
          16, 0, 0);
    }
    __syncthreads();
#pragma unroll
    for (int kk = 0; kk < 2; ++kk) {
      half8 af[4], bf[4];
      int kkh = kk * 4 + quad;
#pragma unroll
      for (int i = 0; i < 4; ++i) {
        int ra = wm + i * 16 + l15;
        af[i] = *(const half8*)(Ash + (ra * 8 + (kkh ^ (ra & 7))) * 8);
        int rb = wn + i * 16 + l15;
        bf[i] = *(const half8*)(Bsh + (rb * 8 + (kkh ^ (rb & 7))) * 8);
      }
#pragma unroll
      for (int i = 0; i < 4; ++i)
#pragma unroll
        for (int j = 0; j < 4; ++j)
          acc[i][j] = __builtin_amdgcn_mfma_f32_16x16x32_f16(af[i], bf[j], acc[i][j], 0, 0, 0);
    }
    __syncthreads();
  }
#pragma unroll
  for (int i = 0; i < 4; ++i)
#pragma unroll
    for (int j = 0; j < 4; ++j) {
      int col = n0 + wn + j * 16 + l15;
      float bv = bias[col];
#pragma unroll
      for (int r = 0; r < 4; ++r) {
        int row = m0 + wm + i * 16 + quad * 4 + r;
        pre[(long)row * 1024 + col] = (_Float16)(acc[i][j][r] + bv);
      }
    }
}

// ---------------------------------------------------------------------------
// rnn v3: 128 blocks (rg 0..7 = blk&7, cg 0..15). Block: rows q0..q0+32,
// cols c0..c0+64. Waves split K (256 each). Weights 128 VGPR/wave, pinned.
// f32 partials in LDS (pad 36, conflict-free). Flag-array sync, prefetch.
// ---------------------------------------------------------------------------
__global__ __launch_bounds__(256, 1) void rnn_kernel(
    const _Float16* __restrict__ pre, const _Float16* __restrict__ whhf,
    _Float16* __restrict__ hbuf, unsigned* ctr, float* __restrict__ out) {
  __shared__ float part[4][64][36];  // [kwave][col][row pad36] = 36 KB
  const int rg = blockIdx.x & 7, cg = blockIdx.x >> 3;
  const int tid = threadIdx.x;
  const int w = tid >> 6, lane = tid & 63;
  const int l15 = lane & 15, quad = lane >> 4;
  const int q0 = rg * 32, c0 = cg * 64;

  // Whh fragments: 64 cols x 256 K (quarter w) = 32 x half8 = 128 VGPR
  half8 bf[8][4];
#pragma unroll
  for (int kk = 0; kk < 8; ++kk)
#pragma unroll
    for (int j = 0; j < 4; ++j) {
      bf[kk][j] = *(const half8*)(whhf + (long)(c0 + j * 16 + l15) * 1024 +
                                  w * 256 + kk * 32 + quad * 8);
      asm volatile("" : "+v"(bf[kk][j]));  // pin: no remat/re-load in loop
    }

  // epilogue ownership: cols cA=tid&31, cB=cA+32; rows orow..orow+3
  const int cA = tid & 31, orow = (tid >> 5) * 4;
  long obA[4], obB[4];
  int hoA[4], hoB[4];
#pragma unroll
  for (int r = 0; r < 4; ++r) {
    int qg = q0 + orow + r;
    int b = qg & 63, ph = qg >> 6;
    obA[r] = (long)(b * 512 + ph) * 1024 + c0 + cA;
    obB[r] = obA[r] + 32;
    hoA[r] = qg * 1024 + c0 + cA;
    hoB[r] = hoA[r] + 32;
  }
  unsigned* flags = ctr + rg * 512;  // 16 flags, 128-B strided
  const int arow = q0 + l15;

  // prefetch pre for k=0
  _Float16 pvA[4], pvB[4];
#pragma unroll
  for (int r = 0; r < 4; ++r) { pvA[r] = pre[obA[r]]; pvB[r] = pre[obB[r]]; }

  for (int k = 0; k < 128; ++k) {
    const _Float16* hcur = hbuf + (long)(k & 1) * 262144;
    _Float16* hnxt = hbuf + (long)((k + 1) & 1) * 262144;
    // A fragments from IC (8 KB per wave per step)
    const _Float16* ap = hcur + (long)arow * 1024 + w * 256 + quad * 8;
    half8 a0[8], a1[8];
#pragma unroll
    for (int kk = 0; kk < 8; ++kk) {
      a0[kk] = ic_load16(ap + kk * 32);
      a1[kk] = ic_load16(ap + 16 * 1024 + kk * 32);
    }
    f32x4 acc[2][4] = {};
#pragma unroll
    for (int kk = 0; kk < 8; ++kk)
#pragma unroll
      for (int j = 0; j < 4; ++j) {
        acc[0][j] = __builtin_amdgcn_mfma_f32_16x16x32_f16(a0[kk], bf[kk][j], acc[0][j], 0, 0, 0);
        acc[1][j] = __builtin_amdgcn_mfma_f32_16x16x32_f16(a1[kk], bf[kk][j], acc[1][j], 0, 0, 0);
      }
#pragma unroll
    for (int t = 0; t < 2; ++t)
#pragma unroll
      for (int j = 0; j < 4; ++j)
        *(f32x4*)&part[w][j * 16 + l15][t * 16 + quad * 4] = acc[t][j];
    __syncthreads();
    // reduce 4 K-partials + pre, tanh
    float hA[4], hB[4];
    {
      f32x4 zA = {(float)pvA[0], (float)pvA[1], (float)pvA[2], (float)pvA[3]};
      f32x4 zB = {(float)pvB[0], (float)pvB[1], (float)pvB[2], (float)pvB[3]};
#pragma unroll
      for (int w4 = 0; w4 < 4; ++w4) {
        f32x4 pA = *(const f32x4*)&part[w4][cA][orow];
        f32x4 pB = *(const f32x4*)&part[w4][cA + 32][orow];
        zA += pA; zB += pB;
      }
#pragma unroll
      for (int r = 0; r < 4; ++r) {
        float eA = __expf(2.f * zA[r]);
        hA[r] = 1.f - 2.f * __builtin_amdgcn_rcpf(eA + 1.f);
        float eB = __expf(2.f * zB[r]);
        hB[r] = 1.f - 2.f * __builtin_amdgcn_rcpf(eB + 1.f);
      }
    }
    if (k < 127) {
      // h stores to IC first (they gate the flag)
#pragma unroll
      for (int r = 0; r < 4; ++r) {
        union { _Float16 h; unsigned short u; } ua, ub;
        ua.h = (_Float16)hA[r]; ub.h = (_Float16)hB[r];
        __hip_atomic_store((unsigned short*)(hnxt + hoA[r]), ua.u,
                           __ATOMIC_RELAXED, __HIP_MEMORY_SCOPE_AGENT);
        __hip_atomic_store((unsigned short*)(hnxt + hoB[r]), ub.u,
                           __ATOMIC_RELAXED, __HIP_MEMORY_SCOPE_AGENT);
      }
      __syncthreads();  // vmcnt(0) drain: h stores acked at IC
      if (tid == 0)
        __hip_atomic_store(&flags[cg * 32], (unsigned)(k + 1),
                           __ATOMIC_RELAXED, __HIP_MEMORY_SCOPE_AGENT);
      // off-chain work during the sync window: out stores + pre prefetch
#pragma unroll
      for (int r = 0; r < 4; ++r) {
        long ko = (long)k * 4096;
        out[obA[r] + ko] = hA[r];
        out[obB[r] + ko] = hB[r];
      }
#pragma unroll
      for (int r = 0; r < 4; ++r) {
        long ko = (long)(k + 1) * 4096;
        pvA[r] = pre[obA[r] + ko];
        pvB[r] = pre[obB[r] + ko];
      }
      // poll 16 flags with 16 lanes
      if (tid < 16) {
        while (__hip_atomic_load(&flags[tid * 32], __ATOMIC_RELAXED,
                                 __HIP_MEMORY_SCOPE_AGENT) < (unsigned)(k + 1))
          __builtin_amdgcn_s_sleep(1);
      }
      __syncthreads();
    } else {
#pragma unroll
      for (int r = 0; r < 4; ++r) {
        long ko = (long)k * 4096;
        out[obA[r] + ko] = hA[r];
        out[obB[r] + ko] = hB[r];
        out[OUT_MAIN + hoA[r]] = hA[r];
        out[OUT_MAIN + hoB[r]] = hB[r];
      }
    }
  }
}

// ---------------------------------------------------------------------------
extern "C" void kernel_launch(void* const* d_in, const int* in_sizes, int n_in,
                              void* d_out, int out_size, void* d_ws, size_t ws_size,
                              hipStream_t stream) {
  const float* x   = (const float*)d_in[0];
  const float* hid = (const float*)d_in[1];
  const float* wih = (const float*)d_in[2];
  const float* whh = (const float*)d_in[3];
  const float* bih = (const float*)d_in[4];
  const float* bhh = (const float*)d_in[5];
  char* ws = (char*)d_ws;
  _Float16* pre  = (_Float16*)(ws + WS_PRE);
  _Float16* wihf = (_Float16*)(ws + WS_WIH);
  _Float16* whhf = (_Float16*)(ws + WS_WHH);
  _Float16* hbuf = (_Float16*)(ws + WS_HBUF);
  float* bias    = (float*)(ws + WS_BIAS);
  unsigned* ctr  = (unsigned*)(ws + WS_CTR);
  float* out     = (float*)d_out;

  hipLaunchKernelGGL(prep_kernel, dim3(256), dim3(256), 0, stream,
                     wih, whh, hid, bih, bhh, wihf, whhf, hbuf, bias, ctr);
  hipLaunchKernelGGL(gemm_pre, dim3(2048), dim3(256), 0, stream, x, wihf, bias, pre);
  hipLaunchKernelGGL(rnn_kernel, dim3(128), dim3(256), 0, stream,
                     pre, whhf, hbuf, ctr, out);
}